// Round 4
// baseline (422.003 us; speedup 1.0000x reference)
//
#include <hip/hip_runtime.h>
#include <hip/hip_bf16.h>
#include <stdint.h>

typedef __attribute__((ext_vector_type(8))) short bf16x8;
typedef __attribute__((ext_vector_type(4))) float f32x4;

__device__ __forceinline__ unsigned f2bf(float f){
  unsigned u = __builtin_bit_cast(unsigned, f);
  return (u + 0x7FFFu + ((u >> 16) & 1u)) >> 16;   // RNE
}
__device__ __forceinline__ float bf2f(unsigned s){
  unsigned u = s << 16; return __builtin_bit_cast(float, u);
}

// ---------- combo: weight cvt + x cvt + per-(rel,dst) degree count ----------
__global__ void k_combo(const float* __restrict__ x,
                        const float* __restrict__ W1, const float* __restrict__ r1,
                        const float* __restrict__ W2, const float* __restrict__ r2,
                        const int* __restrict__ ei, const int* __restrict__ et,
                        short* __restrict__ Wt1, short* __restrict__ Wt2,
                        uint2* __restrict__ xb, int* __restrict__ degr,
                        int N, int E, int WB, int XB){
  int b = blockIdx.x, tid = threadIdx.x;
  if (b < WB){
    int t = b * 256 + tid;
    if (t < 128 * 1152){
      int o = t / 1152, ka = t - o * 1152, r = ka >> 7, k = ka & 127;
      float v = (r < 8) ? W1[(r * 128 + k) * 128 + o] : r1[k * 128 + o];
      Wt1[t] = (short)f2bf(v);
    } else if (t < 128 * 1152 + 64 * 1152){
      int t2 = t - 128 * 1152;
      int o = t2 / 1152, ka = t2 - o * 1152, r = ka >> 7, k = ka & 127;
      float v = (r < 8) ? W2[(r * 128 + k) * 64 + o] : r2[k * 64 + o];
      Wt2[t2] = (short)f2bf(v);
    }
  } else if (b < WB + XB){
    int t = (b - WB) * 256 + tid;
    if (t < N * 32){
      float4 v = reinterpret_cast<const float4*>(x)[t];
      uint2 o;
      o.x = f2bf(v.x) | (f2bf(v.y) << 16);
      o.y = f2bf(v.z) | (f2bf(v.w) << 16);
      xb[t] = o;
    }
  } else {
    int e = (b - WB - XB) * 256 + tid;
    if (e < E){
      unsigned dst = (unsigned)ei[E + e];
      int rel = et[e] & 7;
      if (dst < (unsigned)N) atomicAdd(&degr[rel * N + dst], 1);
    }
  }
}

// ---------- hierarchical exclusive scan over M entries ----------
__global__ void k_scan1(const int* __restrict__ cnt, int* __restrict__ incl,
                        int* __restrict__ bsum, int M){
  __shared__ int s[256];
  int i = blockIdx.x * 256 + threadIdx.x;
  int v = (i < M) ? cnt[i] : 0;
  s[threadIdx.x] = v; __syncthreads();
  for (int d = 1; d < 256; d <<= 1){
    int t = (threadIdx.x >= d) ? s[threadIdx.x - d] : 0;
    __syncthreads();
    s[threadIdx.x] += t;
    __syncthreads();
  }
  if (i < M) incl[i] = s[threadIdx.x];
  if (threadIdx.x == 255) bsum[blockIdx.x] = s[255];
}
__global__ void k_scan2(int* bsum, int NB){
  __shared__ int s[256];
  int t = threadIdx.x;
  int carry = 0;
  for (int c0 = 0; c0 < NB; c0 += 256){
    int i = c0 + t;
    int v = (i < NB) ? bsum[i] : 0;
    s[t] = v; __syncthreads();
    for (int d = 1; d < 256; d <<= 1){
      int u = (t >= d) ? s[t - d] : 0;
      __syncthreads();
      s[t] += u;
      __syncthreads();
    }
    if (i < NB) bsum[i] = s[t] + carry;
    int tot = s[255];
    __syncthreads();
    carry += tot;
  }
}
// offs + packed meta (base | cnt<<20)
__global__ void k_fin(const int* __restrict__ cnt, const int* __restrict__ incl,
                      const int* __restrict__ bsum, int* __restrict__ offs,
                      unsigned* __restrict__ pmeta, int M){
  int i = blockIdx.x * 256 + threadIdx.x;
  if (i >= M) return;
  int base = (blockIdx.x > 0) ? bsum[blockIdx.x - 1] : 0;
  int off = base + incl[i] - cnt[i];
  offs[i] = off;
  int c = cnt[i]; if (c > 4095) c = 4095;
  pmeta[i] = (unsigned)off | ((unsigned)c << 20);
}

// ---------- scatter edges into per-(rel,dst) CSR; payload = src (ushort) ----------
__global__ void k_fill(const int* __restrict__ ei, const int* __restrict__ et,
                       const int* __restrict__ offs, int* __restrict__ fill,
                       unsigned short* __restrict__ idx, int E, int N){
  int e = blockIdx.x * 256 + threadIdx.x;
  if (e >= E) return;
  unsigned src = (unsigned)ei[e];
  unsigned dst = (unsigned)ei[E + e];
  int rel = et[e] & 7;
  if (dst < (unsigned)N){
    int key = rel * N + (int)dst;
    int p = atomicAdd(&fill[key], 1);
    idx[offs[key] + p] = (unsigned short)src;
  }
}

// ---------- fused aggregate+GEMM: barrier-free, wave-independent ----------
// Each wave owns 16 dst rows and a private 4KB sA. 9 K-phases (8 rel + root).
// Gather: lane = (bucket j = lane>>2, 64B chunk c = lane&3); quad reads one
// src row contiguously. B fragments load straight from global (L2-hot Wt).
#define ACC8(d, off) \
  a[(off)+0] += bf2f((d).x & 0xFFFFu); a[(off)+1] += bf2f((d).x >> 16); \
  a[(off)+2] += bf2f((d).y & 0xFFFFu); a[(off)+3] += bf2f((d).y >> 16); \
  a[(off)+4] += bf2f((d).z & 0xFFFFu); a[(off)+5] += bf2f((d).z >> 16); \
  a[(off)+6] += bf2f((d).w & 0xFFFFu); a[(off)+7] += bf2f((d).w >> 16);

template<int NF, int MODE>
__global__ __launch_bounds__(256, 3)
void k_fused(const short* __restrict__ feat, const unsigned* __restrict__ pmeta,
             const unsigned short* __restrict__ idx2, const short* __restrict__ Wt,
             const float* __restrict__ bias, const float* __restrict__ mask,
             void* __restrict__ outp, int N){
  constexpr int BN = NF * 16;
  __shared__ char sA[4][16 * 256];          // per-wave private
  int tid = threadIdx.x, lane = tid & 63, wave = tid >> 6;
  char* mysA = sA[wave];
  int row0 = blockIdx.x * 64 + wave * 16;   // this wave's 16 dst rows
  int j = lane >> 2, c = lane & 3;          // bucket, chunk
  int dstj = row0 + j;
  bool vd = dstj < N;

  f32x4 acc[NF];
  f32x4 z = {0.f, 0.f, 0.f, 0.f};
  #pragma unroll
  for (int n = 0; n < NF; n++) acc[n] = z;

  for (int ph = 0; ph < 9; ph++){
    // ---- aggregate this lane's 64B chunk of its bucket ----
    float a[32];
    #pragma unroll
    for (int t = 0; t < 32; t++) a[t] = 0.f;
    int cnt, base; float inv;
    if (ph < 8){
      unsigned m = vd ? pmeta[ph * N + dstj] : 0u;
      cnt = (int)(m >> 20); base = (int)(m & 0xFFFFFu);
      inv = (cnt > 0) ? 1.0f / (float)cnt : 0.f;
    } else {
      cnt = vd ? 1 : 0; base = 0; inv = 1.0f;
    }
    int srcN = 0;
    if (cnt > 0) srcN = (ph < 8) ? (int)idx2[base] : dstj;
    for (int i = 0; i < cnt; i++){
      int src = srcN;
      if (i + 1 < cnt) srcN = (ph < 8) ? (int)idx2[base + i + 1] : dstj;
      const uint4* rp = reinterpret_cast<const uint4*>(feat + (size_t)src * 128);
      uint4 d0 = rp[c], d1 = rp[4 + c], d2 = rp[8 + c], d3 = rp[12 + c];
      ACC8(d0, 0); ACC8(d1, 8); ACC8(d2, 16); ACC8(d3, 24);
    }
    // ---- scale + pack + swizzled LDS write (4 x b128) ----
    #pragma unroll
    for (int w = 0; w < 4; w++){
      uint4 o;
      o.x = f2bf(a[w*8+0] * inv) | (f2bf(a[w*8+1] * inv) << 16);
      o.y = f2bf(a[w*8+2] * inv) | (f2bf(a[w*8+3] * inv) << 16);
      o.z = f2bf(a[w*8+4] * inv) | (f2bf(a[w*8+5] * inv) << 16);
      o.w = f2bf(a[w*8+6] * inv) | (f2bf(a[w*8+7] * inv) << 16);
      int ch = (w * 4 + c) ^ (j & 7);
      *reinterpret_cast<uint4*>(mysA + j * 256 + (ch << 4)) = o;
    }
    // ---- MFMA: A frag from private LDS, B frag from global (L2-hot) ----
    int r16 = lane & 15, hi = lane >> 4;
    #pragma unroll
    for (int kk = 0; kk < 4; kk++){
      int cha = (kk * 4 + hi) ^ (r16 & 7);
      bf16x8 av = *reinterpret_cast<const bf16x8*>(mysA + r16 * 256 + cha * 16);
      #pragma unroll
      for (int n = 0; n < NF; n++){
        int o = n * 16 + r16;
        bf16x8 bv = *reinterpret_cast<const bf16x8*>(
            Wt + (size_t)o * 1152 + ph * 128 + kk * 32 + hi * 8);
        acc[n] = __builtin_amdgcn_mfma_f32_16x16x32_bf16(av, bv, acc[n], 0, 0, 0);
      }
    }
  }
  // ---- epilogue: D frag col=lane&15, row=(lane>>4)*4+jj ----
  int r16 = lane & 15, hi = lane >> 4;
  #pragma unroll
  for (int n = 0; n < NF; n++){
    int col = n * 16 + r16;
    float bv = bias[col];
    #pragma unroll
    for (int jj = 0; jj < 4; jj++){
      int row = row0 + (hi << 2) + jj;
      if (row < N){
        float v = acc[n][jj] + bv;
        if (MODE == 1){
          v = fmaxf(v, 0.f) * mask[(size_t)row * 128 + col];
          reinterpret_cast<short*>(outp)[(size_t)row * 128 + col] = (short)f2bf(v);
        } else {
          reinterpret_cast<float*>(outp)[(size_t)row * BN + col] = v;
        }
      }
    }
  }
}

extern "C" void kernel_launch(void* const* d_in, const int* in_sizes, int n_in,
                              void* d_out, int out_size, void* d_ws, size_t ws_size,
                              hipStream_t stream){
  const float* x    = (const float*)d_in[0];
  const int*   ei   = (const int*)d_in[1];
  const int*   et   = (const int*)d_in[2];
  const float* W1   = (const float*)d_in[3];
  const float* r1   = (const float*)d_in[4];
  const float* b1   = (const float*)d_in[5];
  const float* W2   = (const float*)d_in[6];
  const float* r2   = (const float*)d_in[7];
  const float* b2   = (const float*)d_in[8];
  const float* mask = (const float*)d_in[9];
  int N = in_sizes[0] / 128;
  int E = in_sizes[2];
  int M8 = 8 * N;

  char* ws = (char*)d_ws;
  short*    xb    = (short*)(ws + 0);            // [N][128] bf16
  short*    hb    = (short*)(ws + 12800000);     // [N][128] bf16
  short*    Wt1   = (short*)(ws + 25600000);     // [128][1152]
  short*    Wt2   = (short*)(ws + 25894912);     // [64][1152]
  int*      degr  = (int*)(ws + 26042368);       // [8N]
  int*      fill  = (int*)(ws + 27642368);       // [8N]
  int*      offs2 = (int*)(ws + 29242368);       // [8N]
  int*      incl  = (int*)(ws + 30842368);       // [8N]
  unsigned* pmeta = (unsigned*)(ws + 32442368);  // [8N] packed base|cnt<<20
  int*      bsum  = (int*)(ws + 34042368);       // [2048]
  unsigned short* idx2 = (unsigned short*)(ws + 34050560); // [E]
  if (ws_size < (size_t)34050560 + (size_t)E * 2) return;

  // zero degr + fill (contiguous)
  hipMemsetAsync(degr, 0, (size_t)M8 * 8, stream);

  int WB = (128*1152 + 64*1152 + 255) / 256;
  int XB = (N * 32 + 255) / 256;
  int EB = (E + 255) / 256;
  int NB = (M8 + 255) / 256;
  k_combo<<<WB + XB + EB, 256, 0, stream>>>(x, W1, r1, W2, r2, ei, et,
                                            Wt1, Wt2, (uint2*)xb, degr, N, E, WB, XB);
  k_scan1<<<NB, 256, 0, stream>>>(degr, incl, bsum, M8);
  k_scan2<<<1, 256, 0, stream>>>(bsum, NB);
  k_fin<<<NB, 256, 0, stream>>>(degr, incl, bsum, offs2, pmeta, M8);
  k_fill<<<EB, 256, 0, stream>>>(ei, et, offs2, fill, idx2, E, N);

  int G = (N + 63) / 64;
  k_fused<8, 1><<<G, 256, 0, stream>>>(xb, pmeta, idx2, Wt1, b1, mask, hb, N);
  k_fused<4, 2><<<G, 256, 0, stream>>>(hb, pmeta, idx2, Wt2, b2, nullptr, d_out, N);
}

// Round 5
// 331.444 us; speedup vs baseline: 1.2732x; 1.2732x over previous
//
#include <hip/hip_runtime.h>
#include <hip/hip_bf16.h>
#include <stdint.h>

typedef __attribute__((ext_vector_type(8))) short bf16x8;
typedef __attribute__((ext_vector_type(4))) float f32x4;

__device__ __forceinline__ unsigned f2bf(float f){
  unsigned u = __builtin_bit_cast(unsigned, f);
  return (u + 0x7FFFu + ((u >> 16) & 1u)) >> 16;   // RNE
}
__device__ __forceinline__ float bf2f(unsigned s){
  unsigned u = s << 16; return __builtin_bit_cast(float, u);
}
__device__ __forceinline__ void add8(float* a, uint4 g){
  a[0] += bf2f(g.x & 0xFFFFu); a[1] += bf2f(g.x >> 16);
  a[2] += bf2f(g.y & 0xFFFFu); a[3] += bf2f(g.y >> 16);
  a[4] += bf2f(g.z & 0xFFFFu); a[5] += bf2f(g.z >> 16);
  a[6] += bf2f(g.w & 0xFFFFu); a[7] += bf2f(g.w >> 16);
}
__device__ __forceinline__ void stage16(const void* g, void* l){
  __builtin_amdgcn_global_load_lds((const __attribute__((address_space(1))) void*)g,
                                   (__attribute__((address_space(3))) void*)l, 16, 0, 0);
}

// ---------- combo: weight cvt (PRE-SWIZZLED layout) + x cvt + degree count ----------
// Wt layout: [ph][o][chunk ch][8 elems] where stored ch = (k>>3) ^ (o&7)
// so a LINEAR global_load_lds copy into LDS yields the swizzled tile directly.
__global__ void k_combo(const float* __restrict__ x,
                        const float* __restrict__ W1, const float* __restrict__ r1,
                        const float* __restrict__ W2, const float* __restrict__ r2,
                        const int* __restrict__ ei, const int* __restrict__ et,
                        short* __restrict__ Wt1, short* __restrict__ Wt2,
                        uint2* __restrict__ xb, int* __restrict__ degr,
                        int N, int E, int WB, int XB){
  int b = blockIdx.x, tid = threadIdx.x;
  if (b < WB){
    int t = b * 256 + tid;
    if (t < 128 * 1152){
      int o = t / 1152, ka = t - o * 1152, ph = ka >> 7, k = ka & 127;
      float v = (ph < 8) ? W1[(ph * 128 + k) * 128 + o] : r1[k * 128 + o];
      int dst = ph * 16384 + o * 128 + (((k >> 3) ^ (o & 7)) << 3) + (k & 7);
      Wt1[dst] = (short)f2bf(v);
    } else if (t < 128 * 1152 + 64 * 1152){
      int t2 = t - 128 * 1152;
      int o = t2 / 1152, ka = t2 - o * 1152, ph = ka >> 7, k = ka & 127;
      float v = (ph < 8) ? W2[(ph * 128 + k) * 64 + o] : r2[k * 64 + o];
      int dst = ph * 8192 + o * 128 + (((k >> 3) ^ (o & 7)) << 3) + (k & 7);
      Wt2[dst] = (short)f2bf(v);
    }
  } else if (b < WB + XB){
    int t = (b - WB) * 256 + tid;
    if (t < N * 32){
      float4 v = reinterpret_cast<const float4*>(x)[t];
      uint2 o;
      o.x = f2bf(v.x) | (f2bf(v.y) << 16);
      o.y = f2bf(v.z) | (f2bf(v.w) << 16);
      xb[t] = o;
    }
  } else {
    int e = (b - WB - XB) * 256 + tid;
    if (e < E){
      unsigned dst = (unsigned)ei[E + e];
      int rel = et[e] & 7;
      if (dst < (unsigned)N) atomicAdd(&degr[rel * N + dst], 1);
    }
  }
}

// ---------- hierarchical exclusive scan over M entries ----------
__global__ void k_scan1(const int* __restrict__ cnt, int* __restrict__ incl,
                        int* __restrict__ bsum, int M){
  __shared__ int s[256];
  int i = blockIdx.x * 256 + threadIdx.x;
  int v = (i < M) ? cnt[i] : 0;
  s[threadIdx.x] = v; __syncthreads();
  for (int d = 1; d < 256; d <<= 1){
    int t = (threadIdx.x >= d) ? s[threadIdx.x - d] : 0;
    __syncthreads();
    s[threadIdx.x] += t;
    __syncthreads();
  }
  if (i < M) incl[i] = s[threadIdx.x];
  if (threadIdx.x == 255) bsum[blockIdx.x] = s[255];
}
__global__ void k_scan2(int* bsum, int NB){
  __shared__ int s[256];
  int t = threadIdx.x;
  int carry = 0;
  for (int c0 = 0; c0 < NB; c0 += 256){
    int i = c0 + t;
    int v = (i < NB) ? bsum[i] : 0;
    s[t] = v; __syncthreads();
    for (int d = 1; d < 256; d <<= 1){
      int u = (t >= d) ? s[t - d] : 0;
      __syncthreads();
      s[t] += u;
      __syncthreads();
    }
    if (i < NB) bsum[i] = s[t] + carry;
    int tot = s[255];
    __syncthreads();
    carry += tot;
  }
}
__global__ void k_fin(const int* __restrict__ cnt, const int* __restrict__ incl,
                      const int* __restrict__ bsum, int* __restrict__ offs,
                      unsigned* __restrict__ pmeta, int M){
  int i = blockIdx.x * 256 + threadIdx.x;
  if (i >= M) return;
  int base = (blockIdx.x > 0) ? bsum[blockIdx.x - 1] : 0;
  int off = base + incl[i] - cnt[i];
  offs[i] = off;
  int c = cnt[i]; if (c > 4095) c = 4095;
  pmeta[i] = (unsigned)off | ((unsigned)c << 20);
}

// ---------- scatter edges into per-(rel,dst) CSR; payload = src (ushort) ----------
__global__ void k_fill(const int* __restrict__ ei, const int* __restrict__ et,
                       const int* __restrict__ offs, int* __restrict__ fill,
                       unsigned short* __restrict__ idx, int E, int N){
  int e = blockIdx.x * 256 + threadIdx.x;
  if (e >= E) return;
  unsigned src = (unsigned)ei[e];
  unsigned dst = (unsigned)ei[E + e];
  int rel = et[e] & 7;
  if (dst < (unsigned)N){
    int key = rel * N + (int)dst;
    int p = atomicAdd(&fill[key], 1);
    idx[offs[key] + p] = (unsigned short)src;
  }
}

// ---------- fused aggregate+GEMM ----------
// Block = 16 dst rows, 256 threads. Stage 1: gather-fill sA[9][16][256B]
// (slot r = tid>>4 owns row r; lane l = tid&15 owns 16B chunk l; deep
// software prefetch across all 9 phases). Stage 2: per-phase GEMM with B
// staged via global_load_lds from pre-swizzled Wt (linear DMA == swizzled).
template<int NF, int MODE>
__global__ __launch_bounds__(256, 2)
void k_fused(const short* __restrict__ feat, const unsigned* __restrict__ pmeta,
             const unsigned short* __restrict__ idx2, const short* __restrict__ Wt,
             const float* __restrict__ bias, const float* __restrict__ mask,
             void* __restrict__ outp, int N){
  constexpr int BN = NF * 16;
  constexpr int NPW = NF / 4;               // n-frags per wave
  __shared__ char sA[9 * 16 * 256];
  __shared__ char sB[BN * 256];
  int tid = threadIdx.x, lane = tid & 63, wave = tid >> 6;
  int row0 = blockIdx.x * 16;

  // ---- stage B(0) immediately (in flight during gathers) ----
  {
    int q4 = BN * 64;                       // bytes per wave
    const char* gsrc = (const char*)Wt;     // phase 0
    #pragma unroll
    for (int i = 0; i < BN / 16; i++){
      int base = wave * q4 + i * 1024;
      stage16(gsrc + base + lane * 16, sB + base);
    }
  }

  // ---- gather-fill sA ----
  {
    int r = tid >> 4, l = tid & 15;
    int dstj = row0 + r;
    bool vd = dstj < N;
    int dsafe = vd ? dstj : 0;
    // meta for 8 relation phases
    unsigned m[8];
    #pragma unroll
    for (int ph = 0; ph < 8; ph++) m[ph] = vd ? pmeta[ph * N + dstj] : 0u;
    // prefetch first two edge srcs per phase
    int s0[8], s1[8];
    #pragma unroll
    for (int ph = 0; ph < 8; ph++){
      int cnt = (int)(m[ph] >> 20), base = (int)(m[ph] & 0xFFFFFu);
      s0[ph] = (cnt > 0) ? (int)idx2[base] : 0;
      s1[ph] = (cnt > 1) ? (int)idx2[base + 1] : 0;
    }
    // prefetch gathers (all independent, deep MLP)
    uint4 g0[8], g1[8], gr;
    #pragma unroll
    for (int ph = 0; ph < 8; ph++)
      g0[ph] = *reinterpret_cast<const uint4*>(feat + (size_t)s0[ph] * 128 + l * 8);
    #pragma unroll
    for (int ph = 0; ph < 8; ph++)
      g1[ph] = *reinterpret_cast<const uint4*>(feat + (size_t)s1[ph] * 128 + l * 8);
    gr = *reinterpret_cast<const uint4*>(feat + (size_t)dsafe * 128 + l * 8);

    int swz = (l ^ (r & 7)) << 4;
    #pragma unroll
    for (int ph = 0; ph < 8; ph++){
      int cnt = (int)(m[ph] >> 20), base = (int)(m[ph] & 0xFFFFFu);
      uint4 ov = {0u, 0u, 0u, 0u};
      if (cnt > 0){
        float a[8];
        a[0]=bf2f(g0[ph].x&0xFFFFu); a[1]=bf2f(g0[ph].x>>16);
        a[2]=bf2f(g0[ph].y&0xFFFFu); a[3]=bf2f(g0[ph].y>>16);
        a[4]=bf2f(g0[ph].z&0xFFFFu); a[5]=bf2f(g0[ph].z>>16);
        a[6]=bf2f(g0[ph].w&0xFFFFu); a[7]=bf2f(g0[ph].w>>16);
        if (cnt > 1) add8(a, g1[ph]);
        for (int i = 2; i < cnt; i++){
          int s = (int)idx2[base + i];
          uint4 gi = *reinterpret_cast<const uint4*>(feat + (size_t)s * 128 + l * 8);
          add8(a, gi);
        }
        float inv = 1.0f / (float)cnt;
        ov.x = f2bf(a[0]*inv) | (f2bf(a[1]*inv) << 16);
        ov.y = f2bf(a[2]*inv) | (f2bf(a[3]*inv) << 16);
        ov.z = f2bf(a[4]*inv) | (f2bf(a[5]*inv) << 16);
        ov.w = f2bf(a[6]*inv) | (f2bf(a[7]*inv) << 16);
      }
      *reinterpret_cast<uint4*>(sA + ph * 4096 + r * 256 + swz) = ov;
    }
    // root phase: own features pass through (already bf16)
    *reinterpret_cast<uint4*>(sA + 8 * 4096 + r * 256 + swz) = gr;
  }

  // ---- GEMM over 9 phases ----
  f32x4 acc[NPW];
  f32x4 z = {0.f, 0.f, 0.f, 0.f};
  #pragma unroll
  for (int nn = 0; nn < NPW; nn++) acc[nn] = z;
  int r16 = lane & 15, q = lane >> 4;

  for (int ph = 0; ph < 9; ph++){
    asm volatile("s_waitcnt vmcnt(0)" ::: "memory");
    __syncthreads();                        // sA (ph==0) + sB(ph) ready
    #pragma unroll
    for (int kk = 0; kk < 4; kk++){
      int ch = ((kk * 4 + q) ^ (r16 & 7)) << 4;
      bf16x8 av = *reinterpret_cast<const bf16x8*>(sA + ph * 4096 + r16 * 256 + ch);
      #pragma unroll
      for (int nn = 0; nn < NPW; nn++){
        int o = (wave * NPW + nn) * 16 + r16;
        bf16x8 bv = *reinterpret_cast<const bf16x8*>(sB + o * 256 + ch);
        acc[nn] = __builtin_amdgcn_mfma_f32_16x16x32_bf16(av, bv, acc[nn], 0, 0, 0);
      }
    }
    __syncthreads();                        // all waves done reading sB
    if (ph < 8){
      int q4 = BN * 64;
      const char* gsrc = (const char*)Wt + (size_t)(ph + 1) * BN * 256;
      #pragma unroll
      for (int i = 0; i < BN / 16; i++){
        int base = wave * q4 + i * 1024;
        stage16(gsrc + base + lane * 16, sB + base);
      }
    }
  }

  // ---- epilogue: D frag col=lane&15, row=(lane>>4)*4+j ----
  #pragma unroll
  for (int nn = 0; nn < NPW; nn++){
    int col = (wave * NPW + nn) * 16 + r16;
    float bv = bias[col];
    #pragma unroll
    for (int j = 0; j < 4; j++){
      int row = row0 + (q << 2) + j;
      if (row < N){
        float v = acc[nn][j] + bv;
        if (MODE == 1){
          v = fmaxf(v, 0.f) * mask[(size_t)row * 128 + col];
          reinterpret_cast<short*>(outp)[(size_t)row * 128 + col] = (short)f2bf(v);
        } else {
          reinterpret_cast<float*>(outp)[(size_t)row * BN + col] = v;
        }
      }
    }
  }
}

extern "C" void kernel_launch(void* const* d_in, const int* in_sizes, int n_in,
                              void* d_out, int out_size, void* d_ws, size_t ws_size,
                              hipStream_t stream){
  const float* x    = (const float*)d_in[0];
  const int*   ei   = (const int*)d_in[1];
  const int*   et   = (const int*)d_in[2];
  const float* W1   = (const float*)d_in[3];
  const float* r1   = (const float*)d_in[4];
  const float* b1   = (const float*)d_in[5];
  const float* W2   = (const float*)d_in[6];
  const float* r2   = (const float*)d_in[7];
  const float* b2   = (const float*)d_in[8];
  const float* mask = (const float*)d_in[9];
  int N = in_sizes[0] / 128;
  int E = in_sizes[2];
  int M8 = 8 * N;

  char* ws = (char*)d_ws;
  short*    xb    = (short*)(ws + 0);            // [N][128] bf16
  short*    hb    = (short*)(ws + 12800000);     // [N][128] bf16
  short*    Wt1   = (short*)(ws + 25600000);     // [9][128][128] swizzled
  short*    Wt2   = (short*)(ws + 25894912);     // [9][64][128] swizzled
  int*      degr  = (int*)(ws + 26042368);       // [8N]
  int*      fill  = (int*)(ws + 27642368);       // [8N]
  int*      offs2 = (int*)(ws + 29242368);       // [8N]
  int*      incl  = (int*)(ws + 30842368);       // [8N]
  unsigned* pmeta = (unsigned*)(ws + 32442368);  // [8N] packed base|cnt<<20
  int*      bsum  = (int*)(ws + 34042368);       // [2048]
  unsigned short* idx2 = (unsigned short*)(ws + 34050560); // [E] (+pad)
  if (ws_size < (size_t)34050560 + (size_t)E * 2 + 64) return;

  hipMemsetAsync(degr, 0, (size_t)M8 * 8, stream);   // degr + fill

  int WB = (128*1152 + 64*1152 + 255) / 256;
  int XB = (N * 32 + 255) / 256;
  int EB = (E + 255) / 256;
  int NB = (M8 + 255) / 256;
  k_combo<<<WB + XB + EB, 256, 0, stream>>>(x, W1, r1, W2, r2, ei, et,
                                            Wt1, Wt2, (uint2*)xb, degr, N, E, WB, XB);
  k_scan1<<<NB, 256, 0, stream>>>(degr, incl, bsum, M8);
  k_scan2<<<1, 256, 0, stream>>>(bsum, NB);
  k_fin<<<NB, 256, 0, stream>>>(degr, incl, bsum, offs2, pmeta, M8);
  k_fill<<<EB, 256, 0, stream>>>(ei, et, offs2, fill, idx2, E, N);

  int G = (N + 15) / 16;
  k_fused<8, 1><<<G, 256, 0, stream>>>(xb, pmeta, idx2, Wt1, b1, mask, hb, N);
  k_fused<4, 2><<<G, 256, 0, stream>>>(hb, pmeta, idx2, Wt2, b2, nullptr, d_out, N);
}

// Round 7
// 285.884 us; speedup vs baseline: 1.4761x; 1.1594x over previous
//
#include <hip/hip_runtime.h>
#include <hip/hip_bf16.h>
#include <stdint.h>

typedef __attribute__((ext_vector_type(8))) short bf16x8;
typedef __attribute__((ext_vector_type(4))) float f32x4;

__device__ __forceinline__ unsigned f2bf(float f){
  unsigned u = __builtin_bit_cast(unsigned, f);
  return (u + 0x7FFFu + ((u >> 16) & 1u)) >> 16;   // RNE
}
__device__ __forceinline__ float bf2f(unsigned s){
  unsigned u = s << 16; return __builtin_bit_cast(float, u);
}
__device__ __forceinline__ void add8(float* a, uint4 g){
  a[0] += bf2f(g.x & 0xFFFFu); a[1] += bf2f(g.x >> 16);
  a[2] += bf2f(g.y & 0xFFFFu); a[3] += bf2f(g.y >> 16);
  a[4] += bf2f(g.z & 0xFFFFu); a[5] += bf2f(g.z >> 16);
  a[6] += bf2f(g.w & 0xFFFFu); a[7] += bf2f(g.w >> 16);
}

// ---------- combo: weight cvt (B-frag layout) + x/mask cvt + degree count ----------
// Wt layout (shorts): [ph][kk][q][o][8]  -> idx = (((ph*4+kk)*4+q)*O + o)*8 + j
// holds W[ph][k][o] with k = kk*32 + q*8 + j. A wave's B-frag load (fixed kk,
// lanes (r16,q), col o = base+r16) reads 4 contiguous 256B clusters.
__global__ void k_combo(const float* __restrict__ x, const float* __restrict__ mask,
                        const float* __restrict__ W1, const float* __restrict__ r1,
                        const float* __restrict__ W2, const float* __restrict__ r2,
                        const int* __restrict__ ei, const int* __restrict__ et,
                        short* __restrict__ Wt1, short* __restrict__ Wt2,
                        uint2* __restrict__ xb, uint2* __restrict__ maskb,
                        int* __restrict__ degr, int N, int E, int WB, int XB){
  int b = blockIdx.x, tid = threadIdx.x;
  if (b < WB){
    int t = b * 256 + tid;
    if (t < 128 * 1152){
      int o = t / 1152, ka = t - o * 1152, ph = ka >> 7, k = ka & 127;
      int kk = k >> 5, q = (k >> 3) & 3, j = k & 7;
      float v = (ph < 8) ? W1[(ph * 128 + k) * 128 + o] : r1[k * 128 + o];
      Wt1[(((ph * 4 + kk) * 4 + q) * 128 + o) * 8 + j] = (short)f2bf(v);
    } else if (t < 128 * 1152 + 64 * 1152){
      int t2 = t - 128 * 1152;
      int o = t2 / 1152, ka = t2 - o * 1152, ph = ka >> 7, k = ka & 127;
      int kk = k >> 5, q = (k >> 3) & 3, j = k & 7;
      float v = (ph < 8) ? W2[(ph * 128 + k) * 64 + o] : r2[k * 64 + o];
      Wt2[(((ph * 4 + kk) * 4 + q) * 64 + o) * 8 + j] = (short)f2bf(v);
    }
  } else if (b < WB + XB){
    int t = (b - WB) * 256 + tid;
    if (t < N * 32){
      float4 v = reinterpret_cast<const float4*>(x)[t];
      uint2 o;
      o.x = f2bf(v.x) | (f2bf(v.y) << 16);
      o.y = f2bf(v.z) | (f2bf(v.w) << 16);
      xb[t] = o;
    } else if (t < N * 64){
      int t2 = t - N * 32;
      float4 v = reinterpret_cast<const float4*>(mask)[t2];
      uint2 o;
      o.x = f2bf(v.x) | (f2bf(v.y) << 16);
      o.y = f2bf(v.z) | (f2bf(v.w) << 16);
      maskb[t2] = o;
    }
  } else {
    int e = (b - WB - XB) * 256 + tid;
    if (e < E){
      unsigned dst = (unsigned)ei[E + e];
      int rel = et[e] & 7;
      if (dst < (unsigned)N) atomicAdd(&degr[rel * N + dst], 1);
    }
  }
}

// ---------- one-pass scan: block-local scan + atomic block base (order-agnostic) ----------
__global__ void k_scan(const int* __restrict__ cnt, int* __restrict__ gcnt,
                       int* __restrict__ offs, unsigned* __restrict__ pmeta, int M){
  __shared__ int s[256];
  __shared__ int sbase;
  int i = blockIdx.x * 256 + threadIdx.x;
  int v = (i < M) ? cnt[i] : 0;
  s[threadIdx.x] = v; __syncthreads();
  for (int d = 1; d < 256; d <<= 1){
    int t = (threadIdx.x >= d) ? s[threadIdx.x - d] : 0;
    __syncthreads();
    s[threadIdx.x] += t;
    __syncthreads();
  }
  if (threadIdx.x == 255) sbase = atomicAdd(gcnt, s[255]);
  __syncthreads();
  if (i < M){
    int off = sbase + s[threadIdx.x] - v;
    offs[i] = off;
    int c = v; if (c > 4095) c = 4095;
    pmeta[i] = (unsigned)off | ((unsigned)c << 20);
  }
}

// ---------- scatter edges into per-(rel,dst) CSR; payload = src (ushort) ----------
__global__ void k_fill(const int* __restrict__ ei, const int* __restrict__ et,
                       const int* __restrict__ offs, int* __restrict__ fill,
                       unsigned short* __restrict__ idx, int E, int N){
  int e = blockIdx.x * 256 + threadIdx.x;
  if (e >= E) return;
  unsigned src = (unsigned)ei[e];
  unsigned dst = (unsigned)ei[E + e];
  int rel = et[e] & 7;
  if (dst < (unsigned)N){
    int key = rel * N + (int)dst;
    int p = atomicAdd(&fill[key], 1);
    idx[offs[key] + p] = (unsigned short)src;
  }
}

// ---------- fused aggregate+GEMM ----------
// Block = 16 dst rows, 256 threads. Stage 1: gather-fill sA[9][16][256B]
// (thread (r=tid>>4, l=tid&15) owns row r chunk l; deep prefetch over phases).
// Stage 2: ONE barrier, then 9-phase MFMA with B double-buffered in registers
// from the B-frag-layout Wt (L2-hot). No sB, no per-phase barriers.
template<int NF, int MODE>
__global__ __launch_bounds__(256, 3)
void k_fused(const short* __restrict__ feat, const unsigned* __restrict__ pmeta,
             const unsigned short* __restrict__ idx2, const short* __restrict__ Wt,
             const float* __restrict__ bias, const short* __restrict__ maskb,
             void* __restrict__ outp, int N){
  constexpr int BN = NF * 16;
  constexpr int NPW = NF / 4;               // B n-frags per wave
  __shared__ char sA[9 * 16 * 256];
  int tid = threadIdx.x, lane = tid & 63, wave = tid >> 6;
  int row0 = blockIdx.x * 16;

  // ---- gather-fill sA ----
  {
    int r = tid >> 4, l = tid & 15;
    int dstj = row0 + r;
    bool vd = dstj < N;
    int dsafe = vd ? dstj : 0;
    unsigned m[8];
    #pragma unroll
    for (int ph = 0; ph < 8; ph++) m[ph] = vd ? pmeta[ph * N + dstj] : 0u;
    int s0[8], s1[8];
    #pragma unroll
    for (int ph = 0; ph < 8; ph++){
      int cnt = (int)(m[ph] >> 20), base = (int)(m[ph] & 0xFFFFFu);
      s0[ph] = (cnt > 0) ? (int)idx2[base] : 0;
      s1[ph] = (cnt > 1) ? (int)idx2[base + 1] : 0;
    }
    uint4 g0[8], g1[8], gr;
    #pragma unroll
    for (int ph = 0; ph < 8; ph++)
      g0[ph] = *reinterpret_cast<const uint4*>(feat + (size_t)s0[ph] * 128 + l * 8);
    #pragma unroll
    for (int ph = 0; ph < 8; ph++)
      g1[ph] = *reinterpret_cast<const uint4*>(feat + (size_t)s1[ph] * 128 + l * 8);
    gr = *reinterpret_cast<const uint4*>(feat + (size_t)dsafe * 128 + l * 8);

    int swz = (l ^ (r & 7)) << 4;
    #pragma unroll
    for (int ph = 0; ph < 8; ph++){
      int cnt = (int)(m[ph] >> 20), base = (int)(m[ph] & 0xFFFFFu);
      uint4 ov = {0u, 0u, 0u, 0u};
      if (cnt > 0){
        float a[8];
        a[0]=bf2f(g0[ph].x&0xFFFFu); a[1]=bf2f(g0[ph].x>>16);
        a[2]=bf2f(g0[ph].y&0xFFFFu); a[3]=bf2f(g0[ph].y>>16);
        a[4]=bf2f(g0[ph].z&0xFFFFu); a[5]=bf2f(g0[ph].z>>16);
        a[6]=bf2f(g0[ph].w&0xFFFFu); a[7]=bf2f(g0[ph].w>>16);
        if (cnt > 1) add8(a, g1[ph]);
        for (int i = 2; i < cnt; i++){
          int s = (int)idx2[base + i];
          uint4 gi = *reinterpret_cast<const uint4*>(feat + (size_t)s * 128 + l * 8);
          add8(a, gi);
        }
        float inv = 1.0f / (float)cnt;
        ov.x = f2bf(a[0]*inv) | (f2bf(a[1]*inv) << 16);
        ov.y = f2bf(a[2]*inv) | (f2bf(a[3]*inv) << 16);
        ov.z = f2bf(a[4]*inv) | (f2bf(a[5]*inv) << 16);
        ov.w = f2bf(a[6]*inv) | (f2bf(a[7]*inv) << 16);
      }
      *reinterpret_cast<uint4*>(sA + ph * 4096 + r * 256 + swz) = ov;
    }
    *reinterpret_cast<uint4*>(sA + 8 * 4096 + r * 256 + swz) = gr;   // root row
  }

  // ---- B phase-0 preload (latency hides under barrier convergence) ----
  int r16 = lane & 15, q = lane >> 4;
  int obase = wave * NPW * 16 + r16;
  bf16x8 bb[2][4][NPW];
  #pragma unroll
  for (int kk = 0; kk < 4; kk++)
    #pragma unroll
    for (int nn = 0; nn < NPW; nn++)
      bb[0][kk][nn] = *reinterpret_cast<const bf16x8*>(
          Wt + ((size_t)(kk * 4 + q) * BN + obase + nn * 16) * 8);

  __syncthreads();                           // the only barrier

  // ---- 9-phase MFMA, B double-buffered in registers ----
  f32x4 acc[NPW];
  f32x4 z = {0.f, 0.f, 0.f, 0.f};
  #pragma unroll
  for (int nn = 0; nn < NPW; nn++) acc[nn] = z;

  #pragma unroll
  for (int ph = 0; ph < 9; ph++){
    if (ph < 8){
      #pragma unroll
      for (int kk = 0; kk < 4; kk++)
        #pragma unroll
        for (int nn = 0; nn < NPW; nn++)
          bb[(ph + 1) & 1][kk][nn] = *reinterpret_cast<const bf16x8*>(
              Wt + ((size_t)(((ph + 1) * 4 + kk) * 4 + q) * BN + obase + nn * 16) * 8);
    }
    #pragma unroll
    for (int kk = 0; kk < 4; kk++){
      int ch = ((kk * 4 + q) ^ (r16 & 7)) << 4;
      bf16x8 av = *reinterpret_cast<const bf16x8*>(sA + ph * 4096 + r16 * 256 + ch);
      #pragma unroll
      for (int nn = 0; nn < NPW; nn++)
        acc[nn] = __builtin_amdgcn_mfma_f32_16x16x32_bf16(av, bb[ph & 1][kk][nn],
                                                          acc[nn], 0, 0, 0);
    }
  }

  // ---- epilogue: D frag col=lane&15, row=(lane>>4)*4+j ----
  #pragma unroll
  for (int nn = 0; nn < NPW; nn++){
    int col = obase + nn * 16;
    float bv = bias[col];
    #pragma unroll
    for (int j = 0; j < 4; j++){
      int row = row0 + (q << 2) + j;
      if (row < N){
        float v = acc[nn][j] + bv;
        if (MODE == 1){
          v = fmaxf(v, 0.f) * bf2f((unsigned)(unsigned short)maskb[(size_t)row * 128 + col]);
          reinterpret_cast<short*>(outp)[(size_t)row * 128 + col] = (short)f2bf(v);
        } else {
          reinterpret_cast<float*>(outp)[(size_t)row * BN + col] = v;
        }
      }
    }
  }
}

extern "C" void kernel_launch(void* const* d_in, const int* in_sizes, int n_in,
                              void* d_out, int out_size, void* d_ws, size_t ws_size,
                              hipStream_t stream){
  const float* x    = (const float*)d_in[0];
  const int*   ei   = (const int*)d_in[1];
  const int*   et   = (const int*)d_in[2];
  const float* W1   = (const float*)d_in[3];
  const float* r1   = (const float*)d_in[4];
  const float* b1   = (const float*)d_in[5];
  const float* W2   = (const float*)d_in[6];
  const float* r2   = (const float*)d_in[7];
  const float* b2   = (const float*)d_in[8];
  const float* mask = (const float*)d_in[9];
  int N = in_sizes[0] / 128;
  int E = in_sizes[2];
  int M8 = 8 * N;

  char* ws = (char*)d_ws;
  short*    xb    = (short*)(ws + 0);            // [N][128] bf16
  short*    hb    = (short*)(ws + 12800000);     // [N][128] bf16
  short*    maskb = (short*)(ws + 25600000);     // [N][128] bf16 (exact: 0 / 1.25)
  short*    Wt1   = (short*)(ws + 38400000);     // [9][4][4][128][8]
  short*    Wt2   = (short*)(ws + 38694912);     // [9][4][4][64][8]
  int*      degr  = (int*)(ws + 38842368);       // [8N]
  int*      fill  = (int*)(ws + 40442368);       // [8N]
  int*      gcnt  = (int*)(ws + 42042368);       // [1] (+pad)
  int*      offs2 = (int*)(ws + 42042432);       // [8N]
  unsigned* pmeta = (unsigned*)(ws + 43642432);  // [8N] packed base|cnt<<20
  unsigned short* idx2 = (unsigned short*)(ws + 45242432); // [E] (+pad)
  if (ws_size < (size_t)45242432 + (size_t)E * 2 + 64) return;

  // zero degr + fill + gcnt (contiguous)
  hipMemsetAsync(degr, 0, (size_t)M8 * 8 + 64, stream);

  int WB = (128*1152 + 64*1152 + 255) / 256;
  int XB = (N * 64 + 255) / 256;
  int EB = (E + 255) / 256;
  int NB = (M8 + 255) / 256;
  k_combo<<<WB + XB + EB, 256, 0, stream>>>(x, mask, W1, r1, W2, r2, ei, et,
                                            Wt1, Wt2, (uint2*)xb, (uint2*)maskb,
                                            degr, N, E, WB, XB);
  k_scan<<<NB, 256, 0, stream>>>(degr, gcnt, offs2, pmeta, M8);
  k_fill<<<EB, 256, 0, stream>>>(ei, et, offs2, fill, idx2, E, N);

  int G = (N + 15) / 16;
  k_fused<8, 1><<<G, 256, 0, stream>>>(xb, pmeta, idx2, Wt1, b1, maskb, hb, N);
  k_fused<4, 2><<<G, 256, 0, stream>>>(hb, pmeta, idx2, Wt2, b2, nullptr, d_out, N);
}

// Round 8
// 281.347 us; speedup vs baseline: 1.4999x; 1.0161x over previous
//
#include <hip/hip_runtime.h>
#include <hip/hip_bf16.h>
#include <stdint.h>

typedef __attribute__((ext_vector_type(8))) short bf16x8;
typedef __attribute__((ext_vector_type(4))) float f32x4;

__device__ __forceinline__ unsigned f2bf(float f){
  unsigned u = __builtin_bit_cast(unsigned, f);
  return (u + 0x7FFFu + ((u >> 16) & 1u)) >> 16;   // RNE
}
__device__ __forceinline__ float bf2f(unsigned s){
  unsigned u = s << 16; return __builtin_bit_cast(float, u);
}
__device__ __forceinline__ void add8(float* a, uint4 g){
  a[0] += bf2f(g.x & 0xFFFFu); a[1] += bf2f(g.x >> 16);
  a[2] += bf2f(g.y & 0xFFFFu); a[3] += bf2f(g.y >> 16);
  a[4] += bf2f(g.z & 0xFFFFu); a[5] += bf2f(g.z >> 16);
  a[6] += bf2f(g.w & 0xFFFFu); a[7] += bf2f(g.w >> 16);
}

// ---------- combo: weight cvt (B-frag layout) + x cvt + degree count ----------
// Wt layout (shorts): [ph][kk][q][o][8]  -> idx = (((ph*4+kk)*4+q)*O + o)*8 + j
// holds W[ph][k][o] with k = kk*32 + q*8 + j. A wave's B-frag load (fixed kk,
// lanes (r16,q), col o = base+r16) reads 4 contiguous 256B clusters.
__global__ void k_combo(const float* __restrict__ x,
                        const float* __restrict__ W1, const float* __restrict__ r1,
                        const float* __restrict__ W2, const float* __restrict__ r2,
                        const int* __restrict__ ei, const int* __restrict__ et,
                        short* __restrict__ Wt1, short* __restrict__ Wt2,
                        uint2* __restrict__ xb, int* __restrict__ degr,
                        int N, int E, int WB, int XB){
  int b = blockIdx.x, tid = threadIdx.x;
  if (b < WB){
    int t = b * 256 + tid;
    if (t < 128 * 1152){
      int o = t / 1152, ka = t - o * 1152, ph = ka >> 7, k = ka & 127;
      int kk = k >> 5, q = (k >> 3) & 3, j = k & 7;
      float v = (ph < 8) ? W1[(ph * 128 + k) * 128 + o] : r1[k * 128 + o];
      Wt1[(((ph * 4 + kk) * 4 + q) * 128 + o) * 8 + j] = (short)f2bf(v);
    } else if (t < 128 * 1152 + 64 * 1152){
      int t2 = t - 128 * 1152;
      int o = t2 / 1152, ka = t2 - o * 1152, ph = ka >> 7, k = ka & 127;
      int kk = k >> 5, q = (k >> 3) & 3, j = k & 7;
      float v = (ph < 8) ? W2[(ph * 128 + k) * 64 + o] : r2[k * 64 + o];
      Wt2[(((ph * 4 + kk) * 4 + q) * 64 + o) * 8 + j] = (short)f2bf(v);
    }
  } else if (b < WB + XB){
    int t = (b - WB) * 256 + tid;
    if (t < N * 32){
      float4 v = reinterpret_cast<const float4*>(x)[t];
      uint2 o;
      o.x = f2bf(v.x) | (f2bf(v.y) << 16);
      o.y = f2bf(v.z) | (f2bf(v.w) << 16);
      xb[t] = o;
    }
  } else {
    int e = (b - WB - XB) * 256 + tid;
    if (e < E){
      unsigned dst = (unsigned)ei[E + e];
      int rel = et[e] & 7;
      if (dst < (unsigned)N) atomicAdd(&degr[rel * N + dst], 1);
    }
  }
}

// ---------- one-pass scan: block-local scan + atomic block base (order-agnostic) ----------
__global__ void k_scan(const int* __restrict__ cnt, int* __restrict__ gcnt,
                       int* __restrict__ offs, unsigned* __restrict__ pmeta, int M){
  __shared__ int s[256];
  __shared__ int sbase;
  int i = blockIdx.x * 256 + threadIdx.x;
  int v = (i < M) ? cnt[i] : 0;
  s[threadIdx.x] = v; __syncthreads();
  for (int d = 1; d < 256; d <<= 1){
    int t = (threadIdx.x >= d) ? s[threadIdx.x - d] : 0;
    __syncthreads();
    s[threadIdx.x] += t;
    __syncthreads();
  }
  if (threadIdx.x == 255) sbase = atomicAdd(gcnt, s[255]);
  __syncthreads();
  if (i < M){
    int off = sbase + s[threadIdx.x] - v;
    offs[i] = off;
    int c = v; if (c > 4095) c = 4095;
    pmeta[i] = (unsigned)off | ((unsigned)c << 20);
  }
}

// ---------- scatter edges into per-(rel,dst) CSR; payload = src (ushort) ----------
__global__ void k_fill(const int* __restrict__ ei, const int* __restrict__ et,
                       const int* __restrict__ offs, int* __restrict__ fill,
                       unsigned short* __restrict__ idx, int E, int N){
  int e = blockIdx.x * 256 + threadIdx.x;
  if (e >= E) return;
  unsigned src = (unsigned)ei[e];
  unsigned dst = (unsigned)ei[E + e];
  int rel = et[e] & 7;
  if (dst < (unsigned)N){
    int key = rel * N + (int)dst;
    int p = atomicAdd(&fill[key], 1);
    idx[offs[key] + p] = (unsigned short)src;
  }
}

// ---------- fused aggregate+GEMM ----------
// Block = 16 dst rows, 256 threads. Stage 1: gather-fill sA[9][16][256B]
// (thread (r=tid>>4, l=tid&15) owns row r chunk l; deep prefetch over phases).
// Stage 2: ONE barrier, then 9-phase MFMA with B double-buffered in registers
// from the B-frag-layout Wt (L2-hot). No sB, no per-phase barriers.
// 4 blocks/CU (LDS 36.9KB x4 = 147KB < 160KB) for gather-latency hiding.
template<int NF, int MODE>
__global__ __launch_bounds__(256, 4)
void k_fused(const short* __restrict__ feat, const unsigned* __restrict__ pmeta,
             const unsigned short* __restrict__ idx2, const short* __restrict__ Wt,
             const float* __restrict__ bias, const float* __restrict__ mask,
             void* __restrict__ outp, int N){
  constexpr int BN = NF * 16;
  constexpr int NPW = NF / 4;               // B n-frags per wave
  __shared__ char sA[9 * 16 * 256];
  int tid = threadIdx.x, lane = tid & 63, wave = tid >> 6;
  int row0 = blockIdx.x * 16;

  // ---- gather-fill sA ----
  {
    int r = tid >> 4, l = tid & 15;
    int dstj = row0 + r;
    bool vd = dstj < N;
    int dsafe = vd ? dstj : 0;
    unsigned m[8];
    #pragma unroll
    for (int ph = 0; ph < 8; ph++) m[ph] = vd ? pmeta[ph * N + dstj] : 0u;
    int s0[8], s1[8];
    #pragma unroll
    for (int ph = 0; ph < 8; ph++){
      int cnt = (int)(m[ph] >> 20), base = (int)(m[ph] & 0xFFFFFu);
      s0[ph] = (cnt > 0) ? (int)idx2[base] : 0;
      s1[ph] = (cnt > 1) ? (int)idx2[base + 1] : 0;
    }
    uint4 g0[8], g1[8], gr;
    #pragma unroll
    for (int ph = 0; ph < 8; ph++)
      g0[ph] = *reinterpret_cast<const uint4*>(feat + (size_t)s0[ph] * 128 + l * 8);
    #pragma unroll
    for (int ph = 0; ph < 8; ph++)
      g1[ph] = *reinterpret_cast<const uint4*>(feat + (size_t)s1[ph] * 128 + l * 8);
    gr = *reinterpret_cast<const uint4*>(feat + (size_t)dsafe * 128 + l * 8);

    int swz = (l ^ (r & 7)) << 4;
    #pragma unroll
    for (int ph = 0; ph < 8; ph++){
      int cnt = (int)(m[ph] >> 20), base = (int)(m[ph] & 0xFFFFFu);
      uint4 ov = {0u, 0u, 0u, 0u};
      if (cnt > 0){
        float a[8];
        a[0]=bf2f(g0[ph].x&0xFFFFu); a[1]=bf2f(g0[ph].x>>16);
        a[2]=bf2f(g0[ph].y&0xFFFFu); a[3]=bf2f(g0[ph].y>>16);
        a[4]=bf2f(g0[ph].z&0xFFFFu); a[5]=bf2f(g0[ph].z>>16);
        a[6]=bf2f(g0[ph].w&0xFFFFu); a[7]=bf2f(g0[ph].w>>16);
        if (cnt > 1) add8(a, g1[ph]);
        for (int i = 2; i < cnt; i++){
          int s = (int)idx2[base + i];
          uint4 gi = *reinterpret_cast<const uint4*>(feat + (size_t)s * 128 + l * 8);
          add8(a, gi);
        }
        float inv = 1.0f / (float)cnt;
        ov.x = f2bf(a[0]*inv) | (f2bf(a[1]*inv) << 16);
        ov.y = f2bf(a[2]*inv) | (f2bf(a[3]*inv) << 16);
        ov.z = f2bf(a[4]*inv) | (f2bf(a[5]*inv) << 16);
        ov.w = f2bf(a[6]*inv) | (f2bf(a[7]*inv) << 16);
      }
      *reinterpret_cast<uint4*>(sA + ph * 4096 + r * 256 + swz) = ov;
    }
    *reinterpret_cast<uint4*>(sA + 8 * 4096 + r * 256 + swz) = gr;   // root row
  }

  // ---- B phase-0 preload (latency hides under barrier convergence) ----
  int r16 = lane & 15, q = lane >> 4;
  int obase = wave * NPW * 16 + r16;
  bf16x8 bb[2][4][NPW];
  #pragma unroll
  for (int kk = 0; kk < 4; kk++)
    #pragma unroll
    for (int nn = 0; nn < NPW; nn++)
      bb[0][kk][nn] = *reinterpret_cast<const bf16x8*>(
          Wt + ((size_t)(kk * 4 + q) * BN + obase + nn * 16) * 8);

  __syncthreads();                           // the only barrier

  // ---- 9-phase MFMA, B double-buffered in registers ----
  f32x4 acc[NPW];
  f32x4 z = {0.f, 0.f, 0.f, 0.f};
  #pragma unroll
  for (int nn = 0; nn < NPW; nn++) acc[nn] = z;

  #pragma unroll
  for (int ph = 0; ph < 9; ph++){
    if (ph < 8){
      #pragma unroll
      for (int kk = 0; kk < 4; kk++)
        #pragma unroll
        for (int nn = 0; nn < NPW; nn++)
          bb[(ph + 1) & 1][kk][nn] = *reinterpret_cast<const bf16x8*>(
              Wt + ((size_t)(((ph + 1) * 4 + kk) * 4 + q) * BN + obase + nn * 16) * 8);
    }
    #pragma unroll
    for (int kk = 0; kk < 4; kk++){
      int ch = ((kk * 4 + q) ^ (r16 & 7)) << 4;
      bf16x8 av = *reinterpret_cast<const bf16x8*>(sA + ph * 4096 + r16 * 256 + ch);
      #pragma unroll
      for (int nn = 0; nn < NPW; nn++)
        acc[nn] = __builtin_amdgcn_mfma_f32_16x16x32_bf16(av, bb[ph & 1][kk][nn],
                                                          acc[nn], 0, 0, 0);
    }
  }

  // ---- epilogue: D frag col=lane&15, row=(lane>>4)*4+j ----
  #pragma unroll
  for (int nn = 0; nn < NPW; nn++){
    int col = obase + nn * 16;
    float bv = bias[col];
    #pragma unroll
    for (int j = 0; j < 4; j++){
      int row = row0 + (q << 2) + j;
      if (row < N){
        float v = acc[nn][j] + bv;
        if (MODE == 1){
          v = fmaxf(v, 0.f) * mask[(size_t)row * 128 + col];
          reinterpret_cast<short*>(outp)[(size_t)row * 128 + col] = (short)f2bf(v);
        } else {
          reinterpret_cast<float*>(outp)[(size_t)row * BN + col] = v;
        }
      }
    }
  }
}

extern "C" void kernel_launch(void* const* d_in, const int* in_sizes, int n_in,
                              void* d_out, int out_size, void* d_ws, size_t ws_size,
                              hipStream_t stream){
  const float* x    = (const float*)d_in[0];
  const int*   ei   = (const int*)d_in[1];
  const int*   et   = (const int*)d_in[2];
  const float* W1   = (const float*)d_in[3];
  const float* r1   = (const float*)d_in[4];
  const float* b1   = (const float*)d_in[5];
  const float* W2   = (const float*)d_in[6];
  const float* r2   = (const float*)d_in[7];
  const float* b2   = (const float*)d_in[8];
  const float* mask = (const float*)d_in[9];
  int N = in_sizes[0] / 128;
  int E = in_sizes[2];
  int M8 = 8 * N;

  char* ws = (char*)d_ws;
  short*    xb    = (short*)(ws + 0);            // [N][128] bf16
  short*    hb    = (short*)(ws + 12800000);     // [N][128] bf16
  short*    Wt1   = (short*)(ws + 25600000);     // [9][4][4][128][8]
  short*    Wt2   = (short*)(ws + 25894912);     // [9][4][4][64][8]
  int*      degr  = (int*)(ws + 26042368);       // [8N]
  int*      fill  = (int*)(ws + 27642368);       // [8N]
  int*      gcnt  = (int*)(ws + 29242368);       // [1] (+pad)
  int*      offs2 = (int*)(ws + 29242432);       // [8N]
  unsigned* pmeta = (unsigned*)(ws + 30842432);  // [8N] packed base|cnt<<20
  unsigned short* idx2 = (unsigned short*)(ws + 32442432); // [E] (+pad)
  if (ws_size < (size_t)32442432 + (size_t)E * 2 + 64) return;

  // zero degr + fill + gcnt (contiguous)
  hipMemsetAsync(degr, 0, (size_t)M8 * 8 + 64, stream);

  int WB = (128*1152 + 64*1152 + 255) / 256;
  int XB = (N * 32 + 255) / 256;
  int EB = (E + 255) / 256;
  int NB = (M8 + 255) / 256;
  k_combo<<<WB + XB + EB, 256, 0, stream>>>(x, W1, r1, W2, r2, ei, et,
                                            Wt1, Wt2, (uint2*)xb, degr, N, E, WB, XB);
  k_scan<<<NB, 256, 0, stream>>>(degr, gcnt, offs2, pmeta, M8);
  k_fill<<<EB, 256, 0, stream>>>(ei, et, offs2, fill, idx2, E, N);

  int G = (N + 15) / 16;
  k_fused<8, 1><<<G, 256, 0, stream>>>(xb, pmeta, idx2, Wt1, b1, mask, hb, N);
  k_fused<4, 2><<<G, 256, 0, stream>>>(hb, pmeta, idx2, Wt2, b2, nullptr, d_out, N);
}